// Round 1
// baseline (76.603 us; speedup 1.0000x reference)
//
#include <hip/hip_runtime.h>

// Gather: out[b,l,:] = table[indices[b,l], :]
// indices: [4096, 200] int32, table: [1000000, 64] f32, out: [4096, 200, 64] f32

constexpr int ROWS = 4096 * 200;   // 819200 gathered rows
constexpr int DIM = 64;            // floats per row
constexpr int VEC_PER_ROW = DIM / 4;  // 16 float4 per row

__global__ __launch_bounds__(256)
void hhe_gather_kernel(const int* __restrict__ indices,
                       const float* __restrict__ table,
                       float* __restrict__ out) {
    const int t = blockIdx.x * blockDim.x + threadIdx.x;
    const int r = t >> 4;        // row id: 16 lanes per row
    const int c = t & 15;        // float4 slot within row
    if (r >= ROWS) return;

    const long long idx = (long long)indices[r];
    const float4* __restrict__ src =
        reinterpret_cast<const float4*>(table + idx * DIM);
    float4* __restrict__ dst =
        reinterpret_cast<float4*>(out + (long long)r * DIM);
    dst[c] = src[c];
}

extern "C" void kernel_launch(void* const* d_in, const int* in_sizes, int n_in,
                              void* d_out, int out_size, void* d_ws, size_t ws_size,
                              hipStream_t stream) {
    const int*   indices = (const int*)d_in[0];
    const float* table   = (const float*)d_in[1];
    float*       out     = (float*)d_out;

    const int total_threads = ROWS * VEC_PER_ROW;      // 13,107,200
    const int block = 256;
    const int grid = (total_threads + block - 1) / block;  // 51200

    hhe_gather_kernel<<<grid, block, 0, stream>>>(indices, table, out);
}

// Round 3
// 64.442 us; speedup vs baseline: 1.1887x; 1.1887x over previous
//
#include <hip/hip_runtime.h>

// Gather: out[b,l,:] = table[indices[b,l], :]
// indices: [4096, 200] int32, table: [1000000, 64] f32, out: [4096, 200, 64] f32

constexpr int ROWS = 4096 * 200;      // 819200 gathered rows
constexpr int DIM = 64;               // floats per row
constexpr int VEC_PER_ROW = DIM / 4;  // 16 float4 per row

typedef float f32x4 __attribute__((ext_vector_type(4)));

__global__ __launch_bounds__(256)
void hhe_gather_kernel(const int* __restrict__ indices,
                       const float* __restrict__ table,
                       float* __restrict__ out) {
    const int t = blockIdx.x * blockDim.x + threadIdx.x;
    const int r = t >> 4;        // row id: 16 lanes per row
    const int c = t & 15;        // float4 slot within row
    if (r >= ROWS) return;

    const long long idx = (long long)indices[r];
    const f32x4* __restrict__ src =
        reinterpret_cast<const f32x4*>(table + idx * DIM);
    f32x4* __restrict__ dst =
        reinterpret_cast<f32x4*>(out + (long long)r * DIM);

    // Cached read of the table row (we want repeats to hit L2/L3)...
    f32x4 v = src[c];
    // ...but non-temporal store of the output stream, so the 210 MB write
    // stream doesn't evict the ~244 MiB table from L3.
    __builtin_nontemporal_store(v, &dst[c]);
}

extern "C" void kernel_launch(void* const* d_in, const int* in_sizes, int n_in,
                              void* d_out, int out_size, void* d_ws, size_t ws_size,
                              hipStream_t stream) {
    const int*   indices = (const int*)d_in[0];
    const float* table   = (const float*)d_in[1];
    float*       out     = (float*)d_out;

    const int total_threads = ROWS * VEC_PER_ROW;      // 13,107,200
    const int block = 256;
    const int grid = (total_threads + block - 1) / block;  // 51200

    hhe_gather_kernel<<<grid, block, 0, stream>>>(indices, table, out);
}